// Round 4
// baseline (789.090 us; speedup 1.0000x reference)
//
#include <hip/hip_runtime.h>
#include <hip/hip_bf16.h>

typedef __bf16 bf16;
typedef __bf16 bf16x8 __attribute__((ext_vector_type(8)));
typedef __bf16 bf16x4 __attribute__((ext_vector_type(4)));
typedef float f32x4 __attribute__((ext_vector_type(4)));

#define S_LEN 2048
#define D_MOD 512
#define NHEAD 8
#define DHEAD 64
#define NBATCH 2

// async global->LDS, 16B per lane; LDS dest is wave-uniform base + lane*16
#define GLOAD_LDS(g, l) __builtin_amdgcn_global_load_lds( \
    (const __attribute__((address_space(1))) unsigned int*)(g), \
    (__attribute__((address_space(3))) unsigned int*)(l), 16, 0, 0)

// flags[1]: mask mode: 0 = 4-byte elems (int32/fp32), 1 = 1-byte, 2 = 2-byte (bf16)
__global__ void detect_kernel(const unsigned char* __restrict__ m, int* __restrict__ flags) {
    __shared__ int s4[4];
    int t = threadIdx.x;
    if (t < 4) s4[t] = 0;
    __syncthreads();
    int c3F = 0, c80p0 = 0, cnzo = 0;
    for (int i = t; i < 4096; i += 256) {
        unsigned b = m[i];
        c3F += (b == 0x3F);
        c80p0 += ((b == 0x80) && ((i & 3) == 0));
        cnzo += ((b != 0) && ((i & 3) != 0));
    }
    atomicAdd(&s4[1], c3F);
    atomicAdd(&s4[2], c80p0);
    atomicAdd(&s4[3], cnzo);
    __syncthreads();
    if (t == 0) {
        int mode;
        if (s4[1] > 0)      mode = (s4[2] > 0) ? 2 : 0;
        else if (s4[3] > 0) mode = 1;
        else                mode = 0;
        flags[1] = mode;
    }
}

__global__ void maskconv_kernel(const unsigned char* __restrict__ m,
                                const int* __restrict__ flags,
                                unsigned char* __restrict__ out) {
    long i = ((long)blockIdx.x * 256 + threadIdx.x) * 4;
    int mode = flags[1];
    uchar4 v;
    if (mode == 0) {
        const int* mi = (const int*)m;
        v.x = (unsigned char)(mi[i + 0] != 0);
        v.y = (unsigned char)(mi[i + 1] != 0);
        v.z = (unsigned char)(mi[i + 2] != 0);
        v.w = (unsigned char)(mi[i + 3] != 0);
    } else if (mode == 1) {
        uchar4 r = *(const uchar4*)(m + i);
        v.x = (r.x != 0); v.y = (r.y != 0); v.z = (r.z != 0); v.w = (r.w != 0);
    } else {
        const unsigned short* ms = (const unsigned short*)m;
        v.x = (unsigned char)(ms[i + 0] != 0);
        v.y = (unsigned char)(ms[i + 1] != 0);
        v.z = (unsigned char)(ms[i + 2] != 0);
        v.w = (unsigned char)(ms[i + 3] != 0);
    }
    *(uchar4*)(out + i) = v;
}

// ---------- fp32 -> (hi,lo) bf16 split, elementwise ----------
__global__ __launch_bounds__(256) void packA(const float* __restrict__ src,
                                             bf16* __restrict__ outh,
                                             bf16* __restrict__ outl) {
    long i = ((long)blockIdx.x * 256 + threadIdx.x) * 4;
    f32x4 v = *(const f32x4*)(src + i);
    bf16x4 h, l;
    #pragma unroll
    for (int j = 0; j < 4; ++j) {
        bf16 hh = (bf16)v[j];
        h[j] = hh;
        l[j] = (bf16)(v[j] - (float)hh);
    }
    *(bf16x4*)(outh + i) = h;
    *(bf16x4*)(outl + i) = l;
}

// ---------- W [K,N] fp32 -> W^T (hi,lo) bf16 [N,K], tiled transpose ----------
__global__ __launch_bounds__(256) void packWT(const float* __restrict__ W,
                                              bf16* __restrict__ outh,
                                              bf16* __restrict__ outl,
                                              int K, int N) {
    __shared__ float tile[64][65];
    int n0 = blockIdx.x * 64, k0 = blockIdx.y * 64;
    int t = threadIdx.x, tx = t & 63, ty = t >> 6;
    #pragma unroll
    for (int r = ty; r < 64; r += 4)
        tile[r][tx] = W[(long)(k0 + r) * N + n0 + tx];
    __syncthreads();
    #pragma unroll
    for (int r = ty; r < 64; r += 4) {
        float v = tile[tx][r];            // = W[k0+tx][n0+r]
        bf16 h = (bf16)v;
        long idx = (long)(n0 + r) * K + k0 + tx;
        outh[idx] = h;
        outl[idx] = (bf16)(v - (float)h);
    }
}

// ---------- 3x fused packWT for 512x512 QKV weights (z picks source) ----------
__global__ __launch_bounds__(256) void packWT3(const float* __restrict__ Wa,
                                               const float* __restrict__ Wb,
                                               const float* __restrict__ Wc,
                                               bf16* __restrict__ outh,
                                               bf16* __restrict__ outl) {
    __shared__ float tile[64][65];
    const float* W = blockIdx.z == 0 ? Wa : (blockIdx.z == 1 ? Wb : Wc);
    long dofs = (long)blockIdx.z * 512 * 512;
    int n0 = blockIdx.x * 64, k0 = blockIdx.y * 64;
    int t = threadIdx.x, tx = t & 63, ty = t >> 6;
    #pragma unroll
    for (int r = ty; r < 64; r += 4)
        tile[r][tx] = W[(long)(k0 + r) * 512 + n0 + tx];
    __syncthreads();
    #pragma unroll
    for (int r = ty; r < 64; r += 4) {
        float v = tile[tx][r];
        bf16 h = (bf16)v;
        long idx = dofs + (long)(n0 + r) * 512 + k0 + tx;
        outh[idx] = h;
        outl[idx] = (bf16)(v - (float)h);
    }
}

__global__ void concat_bias(const float* __restrict__ a, const float* __restrict__ b,
                            const float* __restrict__ c, float* __restrict__ o) {
    int t = blockIdx.x * 256 + threadIdx.x;
    o[t] = (t < 512) ? a[t] : (t < 1024 ? b[t - 512] : c[t - 1024]);
}

// ---------- split-bf16 MFMA GEMM, shape-adaptive tile ----------
// C[M,N] = (Ahi+Alo)[M,K] @ (Bth+Btl)[N,K]^T ; 3-term: hi*hi + hi*lo + lo*hi.
// LDS is one flat chunk-ordered region: [Ahi BM | Alo BM | Bhi BN | Blo BN] rows x 32.
// EPI 1: +bias, relu -> (hi,lo) bf16 pair
// EPI 2: +bias +res  -> fp32
// EPI 3: fused QKV: n<512 -> outh bf16 ; n<1024 -> outl bf16 ; else outf fp32
template<int BM, int BN, int WR, int WC, int EPI>
__global__ __launch_bounds__(256) void mgemm(
    const bf16* __restrict__ Ahi, const bf16* __restrict__ Alo,
    const bf16* __restrict__ Bth, const bf16* __restrict__ Btl,
    const float* __restrict__ bias, const float* __restrict__ res,
    float* __restrict__ outf, bf16* __restrict__ outh, bf16* __restrict__ outl,
    int M, int N, int K)
{
    constexpr int WM = BM / WR, WN = BN / WC;
    constexpr int FI = WM / 16, FJ = WN / 16;
    constexpr int NCH = (2 * BM + 2 * BN) / 16;   // 16-row chunks
    constexpr int NPW = NCH / 4;                  // chunks per wave
    __shared__ bf16 lds[(2 * BM + 2 * BN) * 32];

    int t = threadIdx.x;
    int lane = t & 63, wave = t >> 6;
    int lm = lane & 15, quad = lane >> 4;
    int wr = wave / WC, wc = wave % WC;
    int m0 = blockIdx.y * BM, n0 = blockIdx.x * BN;

    // per-chunk global pointers (16 rows x 32 cols each; 4 lanes/row x 16B)
    const bf16* gp[NPW];
    #pragma unroll
    for (int ci = 0; ci < NPW; ++ci) {
        int c = wave * NPW + ci;
        const bf16* src; int row0;
        if (c < BM / 16)                  { src = Ahi; row0 = m0 + c * 16; }
        else if (c < 2 * BM / 16)         { src = Alo; row0 = m0 + (c - BM / 16) * 16; }
        else if (c < (2 * BM + BN) / 16)  { src = Bth; row0 = n0 + (c - 2 * BM / 16) * 16; }
        else                              { src = Btl; row0 = n0 + (c - (2 * BM + BN) / 16) * 16; }
        gp[ci] = src + (long)(row0 + (lane >> 2)) * K + (lane & 3) * 8;
    }
    bf16* ldsw = &lds[wave * NPW * 512];

    f32x4 acc[FI][FJ] = {};

    for (int k0 = 0; k0 < K; k0 += 32) {
        __syncthreads();                       // all waves done reading prev tile
        #pragma unroll
        for (int ci = 0; ci < NPW; ++ci)
            GLOAD_LDS(gp[ci] + k0, ldsw + ci * 512);
        __syncthreads();                       // drains vmcnt -> LDS valid

        bf16x8 ah[FI], al[FI];
        #pragma unroll
        for (int i = 0; i < FI; ++i) {
            int row = wr * WM + i * 16 + lm;
            ah[i] = *(const bf16x8*)&lds[row * 32 + quad * 8];
            al[i] = *(const bf16x8*)&lds[(BM + row) * 32 + quad * 8];
        }
        #pragma unroll
        for (int j = 0; j < FJ; ++j) {
            int row = wc * WN + j * 16 + lm;
            bf16x8 bh = *(const bf16x8*)&lds[(2 * BM + row) * 32 + quad * 8];
            bf16x8 bl = *(const bf16x8*)&lds[(2 * BM + BN + row) * 32 + quad * 8];
            #pragma unroll
            for (int i = 0; i < FI; ++i) {
                acc[i][j] = __builtin_amdgcn_mfma_f32_16x16x32_bf16(ah[i], bh, acc[i][j], 0, 0, 0);
                acc[i][j] = __builtin_amdgcn_mfma_f32_16x16x32_bf16(ah[i], bl, acc[i][j], 0, 0, 0);
                acc[i][j] = __builtin_amdgcn_mfma_f32_16x16x32_bf16(al[i], bh, acc[i][j], 0, 0, 0);
            }
        }
    }

    #pragma unroll
    for (int j = 0; j < FJ; ++j) {
        int gn = n0 + wc * WN + j * 16 + lm;
        float bv = bias[gn];
        #pragma unroll
        for (int i = 0; i < FI; ++i) {
            #pragma unroll
            for (int r = 0; r < 4; ++r) {
                int gm = m0 + wr * WM + i * 16 + quad * 4 + r;
                float v = acc[i][j][r] + bv;
                if (EPI == 3) {
                    if (gn < 512)       outh[(long)gm * 512 + gn] = (bf16)v;
                    else if (gn < 1024) outl[(long)gm * 512 + gn - 512] = (bf16)v;
                    else                outf[(long)gm * 512 + gn - 1024] = v;
                } else {
                    long idx = (long)gm * N + gn;
                    if (EPI == 1) {
                        v = fmaxf(v, 0.f);
                        bf16 h = (bf16)v;
                        outh[idx] = h;
                        outl[idx] = (bf16)(v - (float)h);
                    } else {
                        if (EPI == 2) v += res[idx];
                        outf[idx] = v;
                    }
                }
            }
        }
    }
}

// ---------- V fp32 [B*S, H*64] -> bf16 V^T [B,H,64,S], LDS-tiled (coalesced) ----------
__global__ __launch_bounds__(256) void pack_vT(const float* __restrict__ src,
                                               bf16* __restrict__ dst) {
    __shared__ float tile[64][65];
    int s0 = blockIdx.x * 64;
    int bh = blockIdx.y;             // b*8+h
    int b = bh >> 3, h = bh & 7;
    int t = threadIdx.x, tx = t & 63, ty = t >> 6;
    #pragma unroll
    for (int r = ty; r < 64; r += 4)
        tile[r][tx] = src[(long)(b * S_LEN + s0 + r) * 512 + h * 64 + tx];
    __syncthreads();
    #pragma unroll
    for (int d = ty; d < 64; d += 4)
        dst[((long)bh * 64 + d) * S_LEN + s0 + tx] = (bf16)tile[tx][d];
}

// ---------- MFMA attention: SINGLE-PASS online softmax ----------
// Writes raw masked scores into attnO during the pass, tracks online (m,l),
// accumulates PV with unnormalized exp(s - m_running), rescaling oacc when m grows.
// Final: ctx = oacc/l (bf16 hi/lo), then an in-kernel sweep normalizes the
// block's own 64x2048 attnO stripe (L2/L3-hot): p = exp(s - m)*(1/l).
// Q,K layout: bf16 [B*S, 512] (head h at col h*64). V^T layout: bf16 [B,H,64,S].
__global__ __launch_bounds__(256) void attn_kernel(
    const bf16* __restrict__ Q, const bf16* __restrict__ Kg,
    const bf16* __restrict__ Vt, const unsigned char* __restrict__ mask8,
    float* __restrict__ attnO, bf16* __restrict__ ctxh, bf16* __restrict__ ctxl)
{
    __shared__ bf16 Qs[64][72];
    __shared__ bf16 Ks[64][72];
    __shared__ bf16 Vs[64][72];
    __shared__ bf16 Ps[64][72];
    __shared__ float mlds[64];
    __shared__ float llds[64];

    int t = threadIdx.x;
    int qt = blockIdx.x & 31, bh = blockIdx.x >> 5;
    int b_ = bh >> 3, h_ = bh & 7;
    int q0 = qt * 64;
    int lane = t & 63, wave = t >> 6;
    int lm = lane & 15, quad = lane >> 4, q8 = quad * 8;
    int sr = t >> 2, sc = (t & 3) * 16;

    const bf16* Qp = Q + (((long)(b_ * S_LEN + q0 + sr)) << 9) + (h_ << 6) + sc;
    *(bf16x8*)&Qs[sr][sc]     = *(const bf16x8*)(Qp);
    *(bf16x8*)&Qs[sr][sc + 8] = *(const bf16x8*)(Qp + 8);
    __syncthreads();
    // Q fragments are loop-invariant: hoist
    bf16x8 a0 = *(const bf16x8*)&Qs[wave * 16 + lm][q8];
    bf16x8 a1 = *(const bf16x8*)&Qs[wave * 16 + lm][32 + q8];

    float mrow[4], lrow[4];
    #pragma unroll
    for (int r = 0; r < 4; ++r) { mrow[r] = -1e30f; lrow[r] = 0.f; }
    f32x4 oacc[4] = {};

    const unsigned char* Mbase = mask8 + (long)b_ * S_LEN * S_LEN;
    float* attnBase = attnO + (long)bh * S_LEN * S_LEN;
    const bf16* Vbase = Vt + (long)bh * (DHEAD * S_LEN);

    for (int kt = 0; kt < 32; ++kt) {
        int k0 = kt * 64;
        __syncthreads();
        const bf16* Kp = Kg + (((long)(b_ * S_LEN + k0 + sr)) << 9) + (h_ << 6) + sc;
        *(bf16x8*)&Ks[sr][sc]     = *(const bf16x8*)(Kp);
        *(bf16x8*)&Ks[sr][sc + 8] = *(const bf16x8*)(Kp + 8);
        const bf16* Vp = Vbase + (long)sr * S_LEN + k0 + sc;
        *(bf16x8*)&Vs[sr][sc]     = *(const bf16x8*)(Vp);
        *(bf16x8*)&Vs[sr][sc + 8] = *(const bf16x8*)(Vp + 8);
        __syncthreads();

        f32x4 sacc[4] = {};
        #pragma unroll
        for (int tn = 0; tn < 4; ++tn) {
            bf16x8 b0 = *(const bf16x8*)&Ks[tn * 16 + lm][q8];
            bf16x8 b1 = *(const bf16x8*)&Ks[tn * 16 + lm][32 + q8];
            sacc[tn] = __builtin_amdgcn_mfma_f32_16x16x32_bf16(a0, b0, sacc[tn], 0, 0, 0);
            sacc[tn] = __builtin_amdgcn_mfma_f32_16x16x32_bf16(a1, b1, sacc[tn], 0, 0, 0);
        }

        float scr[4];
        #pragma unroll
        for (int r = 0; r < 4; ++r) {
            int grow = q0 + wave * 16 + quad * 4 + r;
            const unsigned char* Mr = Mbase + (long)grow * S_LEN + k0 + lm;
            float sv[4];
            float tmax = -1e30f;
            #pragma unroll
            for (int tn = 0; tn < 4; ++tn) {
                float s = sacc[tn][r] * 0.125f;
                if (Mr[tn * 16]) s = -1e9f;
                sv[tn] = s;
                tmax = fmaxf(tmax, s);
                attnBase[(long)grow * S_LEN + k0 + tn * 16 + lm] = s;  // raw score stash
            }
            #pragma unroll
            for (int off = 8; off; off >>= 1) tmax = fmaxf(tmax, __shfl_xor(tmax, off));
            float mnew = fmaxf(mrow[r], tmax);
            float sc0 = __expf(mrow[r] - mnew);
            float es = 0.f;
            #pragma unroll
            for (int tn = 0; tn < 4; ++tn) {
                float pe = __expf(sv[tn] - mnew);
                es += pe;
                Ps[wave * 16 + quad * 4 + r][tn * 16 + lm] = (bf16)pe;
            }
            #pragma unroll
            for (int off = 8; off; off >>= 1) es += __shfl_xor(es, off);
            lrow[r] = lrow[r] * sc0 + es;
            mrow[r] = mnew;
            scr[r] = sc0;
        }
        // rescale running PV accumulator before adding this tile
        #pragma unroll
        for (int td = 0; td < 4; ++td)
            #pragma unroll
            for (int r = 0; r < 4; ++r) oacc[td][r] *= scr[r];

        __syncthreads();
        bf16x8 pa0 = *(const bf16x8*)&Ps[wave * 16 + lm][q8];
        bf16x8 pa1 = *(const bf16x8*)&Ps[wave * 16 + lm][32 + q8];
        #pragma unroll
        for (int td = 0; td < 4; ++td) {
            bf16x8 v0 = *(const bf16x8*)&Vs[td * 16 + lm][q8];
            bf16x8 v1 = *(const bf16x8*)&Vs[td * 16 + lm][32 + q8];
            oacc[td] = __builtin_amdgcn_mfma_f32_16x16x32_bf16(pa0, v0, oacc[td], 0, 0, 0);
            oacc[td] = __builtin_amdgcn_mfma_f32_16x16x32_bf16(pa1, v1, oacc[td], 0, 0, 0);
        }
    }

    float rl[4];
    #pragma unroll
    for (int r = 0; r < 4; ++r) rl[r] = 1.f / lrow[r];

    // ctx bf16 hi/lo [B*S, H*64] (normalize by 1/l)
    #pragma unroll
    for (int td = 0; td < 4; ++td)
    #pragma unroll
    for (int r = 0; r < 4; ++r) {
        int grow = q0 + wave * 16 + quad * 4 + r;
        long cidx = (((long)(b_ * S_LEN + grow)) << 9) + (h_ << 6) + td * 16 + lm;
        float v = oacc[td][r] * rl[r];
        bf16 h = (bf16)v;
        ctxh[cidx] = h;
        ctxl[cidx] = (bf16)(v - (float)h);
    }

    // publish per-row (m, 1/l) and normalize this block's attnO stripe
    if (lm == 0) {
        #pragma unroll
        for (int r = 0; r < 4; ++r) {
            int row = wave * 16 + quad * 4 + r;
            mlds[row] = mrow[r];
            llds[row] = rl[r];
        }
    }
    __syncthreads();
    int rr = t >> 2;
    float m_ = mlds[rr], rl_ = llds[rr];
    f32x4* base = (f32x4*)(attnBase + (((long)(q0 + rr)) << 11) + (t & 3) * 512);
    #pragma unroll 4
    for (int i = 0; i < 128; ++i) {
        f32x4 v = base[i];
        v[0] = __expf(v[0] - m_) * rl_;
        v[1] = __expf(v[1] - m_) * rl_;
        v[2] = __expf(v[2] - m_) * rl_;
        v[3] = __expf(v[3] - m_) * rl_;
        base[i] = v;
    }
}

// ---------- layernorm over D=512; optional hi/lo bf16 split outputs ----------
template<int SPLIT>
__global__ __launch_bounds__(256) void ln_kernel(
    const float* __restrict__ X, const float* __restrict__ g,
    const float* __restrict__ bb, float* __restrict__ out,
    bf16* __restrict__ oh, bf16* __restrict__ ol)
{
    __shared__ float red[8];
    int row = blockIdx.x, t = threadIdx.x;
    float x0 = X[(long)row * 512 + t];
    float x1 = X[(long)row * 512 + 256 + t];
    float s = x0 + x1, ss = x0 * x0 + x1 * x1;
    #pragma unroll
    for (int off = 32; off; off >>= 1) { s += __shfl_xor(s, off); ss += __shfl_xor(ss, off); }
    if ((t & 63) == 0) { red[t >> 6] = s; red[4 + (t >> 6)] = ss; }
    __syncthreads();
    float S_ = red[0] + red[1] + red[2] + red[3];
    float SS = red[4] + red[5] + red[6] + red[7];
    float mu = S_ * (1.f / 512.f);
    float var = SS * (1.f / 512.f) - mu * mu;
    float is = rsqrtf(var + 1e-5f);
    float o0 = (x0 - mu) * is * g[t]       + bb[t];
    float o1 = (x1 - mu) * is * g[t + 256] + bb[t + 256];
    out[(long)row * 512 + t]       = o0;
    out[(long)row * 512 + 256 + t] = o1;
    if (SPLIT) {
        bf16 h0 = (bf16)o0, h1 = (bf16)o1;
        oh[(long)row * 512 + t]       = h0;
        oh[(long)row * 512 + 256 + t] = h1;
        ol[(long)row * 512 + t]       = (bf16)(o0 - (float)h0);
        ol[(long)row * 512 + 256 + t] = (bf16)(o1 - (float)h1);
    }
}

// ---------------- host launch ----------------
extern "C" void kernel_launch(void* const* d_in, const int* in_sizes, int n_in,
                              void* d_out, int out_size, void* d_ws, size_t ws_size,
                              hipStream_t stream)
{
    const float* x = (const float*)d_in[0];
    const unsigned char* maskraw = (const unsigned char*)d_in[1];
    const float* Wq = (const float*)d_in[2];  const float* bq = (const float*)d_in[3];
    const float* Wk = (const float*)d_in[4];  const float* bk = (const float*)d_in[5];
    const float* Wv = (const float*)d_in[6];  const float* bv = (const float*)d_in[7];
    const float* Wo = (const float*)d_in[8];  const float* bo = (const float*)d_in[9];
    const float* ln1g = (const float*)d_in[10]; const float* ln1b = (const float*)d_in[11];
    const float* W1 = (const float*)d_in[12]; const float* b1f = (const float*)d_in[13];
    const float* W2 = (const float*)d_in[14]; const float* b2f = (const float*)d_in[15];
    const float* ln2g = (const float*)d_in[16]; const float* ln2b = (const float*)d_in[17];

    // OUTPUTS ARE FP32: out [B*S*D] then attn [B*H*S*S], concatenated flat.
    float* outMain = (float*)d_out;
    float* outAttn = outMain + (size_t)NBATCH * S_LEN * D_MOD;

    char* w = (char*)d_ws;
    size_t off = 0;
    auto alloc = [&](size_t bytes) -> char* {
        char* p = w + off;
        off += (bytes + 255) & ~(size_t)255;
        return p;
    };
    const size_t MB = 1024 * 1024;
    int* flags = (int*)alloc(256);
    unsigned char* mask8 = (unsigned char*)alloc(8 * MB);

    // ---- 36MB contiguous span (later aliased by hh/hl for FFN hidden) ----
    bf16* xh   = (bf16*)alloc(4 * MB);   // input x hi  [4096,512]
    bf16* xl   = (bf16*)alloc(4 * MB);   // input x lo
    bf16* Qb   = (bf16*)alloc(4 * MB);   // Q bf16 [4096,512]
    bf16* Kb   = (bf16*)alloc(4 * MB);   // K bf16 [4096,512]
    float* vf  = (float*)alloc(8 * MB);  // V fp32 [4096,512]
    bf16* Vtb  = (bf16*)alloc(4 * MB);   // V^T bf16 [B,H,64,S]
    bf16* ctxh = (bf16*)alloc(4 * MB);   // ctx hi
    bf16* ctxl = (bf16*)alloc(4 * MB);   // ctx lo
    // aliases: FFN hidden [4096,2048] bf16 hi/lo, 16MB each
    bf16* hh = xh;            // covers xh,xl,Qb,Kb   (all dead before FFN1)
    bf16* hl = (bf16*)vf;     // covers vf,Vtb,ctxh   (all dead before FFN1)

    float* tmp   = (float*)alloc(8 * MB);
    float* aoutf = (float*)alloc(8 * MB);
    bf16* aouth  = (bf16*)alloc(4 * MB);
    bf16* aoutl  = (bf16*)alloc(4 * MB);

    // weights: transposed+split
    bf16* WqkvTh = (bf16*)alloc((size_t)1536 * 512 * 2);
    bf16* WqkvTl = (bf16*)alloc((size_t)1536 * 512 * 2);
    bf16* WoTh = (bf16*)alloc(512 * 1024); bf16* WoTl = (bf16*)alloc(512 * 1024);
    bf16* W1Th = (bf16*)alloc(2 * MB);     bf16* W1Tl = (bf16*)alloc(2 * MB);
    bf16* W2Th = (bf16*)alloc(2 * MB);     bf16* W2Tl = (bf16*)alloc(2 * MB);
    float* bqkv = (float*)alloc(1536 * 4);

    const int M = NBATCH * S_LEN;  // 4096

    detect_kernel<<<1, 256, 0, stream>>>(maskraw, flags);
    maskconv_kernel<<<(NBATCH * S_LEN * S_LEN) / 1024, 256, 0, stream>>>(maskraw, flags, mask8);

    // weight prep
    concat_bias<<<6, 256, 0, stream>>>(bq, bk, bv, bqkv);
    packWT3<<<dim3(8, 8, 3), 256, 0, stream>>>(Wq, Wk, Wv, WqkvTh, WqkvTl);
    packWT<<<dim3(8, 8), 256, 0, stream>>>(Wo, WoTh, WoTl, 512, 512);
    packWT<<<dim3(32, 8), 256, 0, stream>>>(W1, W1Th, W1Tl, 512, 2048);
    packWT<<<dim3(8, 32), 256, 0, stream>>>(W2, W2Th, W2Tl, 2048, 512);

    // fused QKV projection -> Qb/Kb bf16 (attn layout) + vf fp32
    packA<<<(M * 512) / 1024, 256, 0, stream>>>(x, xh, xl);
    mgemm<64, 128, 1, 4, 3><<<dim3(12, 64), 256, 0, stream>>>(
        xh, xl, WqkvTh, WqkvTl, bqkv, nullptr, vf, Qb, Kb, M, 1536, 512);
    pack_vT<<<dim3(32, 16), 256, 0, stream>>>(vf, Vtb);

    // fused single-pass MFMA attention: fp32 probs (Output 1) + bf16 hi/lo context
    attn_kernel<<<512, 256, 0, stream>>>(Qb, Kb, Vtb, mask8, outAttn, ctxh, ctxl);

    // out-proj + residual, then LN1 (emits hi/lo for FFN1)
    mgemm<64, 64, 2, 2, 2><<<dim3(8, 64), 256, 0, stream>>>(
        ctxh, ctxl, WoTh, WoTl, bo, x, tmp, nullptr, nullptr, M, 512, 512);
    ln_kernel<1><<<M, 256, 0, stream>>>(tmp, ln1g, ln1b, aoutf, aouth, aoutl);

    // FFN: W1 emits relu'd (hi,lo) bf16 directly
    mgemm<128, 128, 2, 2, 1><<<dim3(16, 32), 256, 0, stream>>>(
        aouth, aoutl, W1Th, W1Tl, b1f, nullptr, nullptr, hh, hl, M, 2048, 512);
    mgemm<64, 64, 2, 2, 2><<<dim3(8, 64), 256, 0, stream>>>(
        hh, hl, W2Th, W2Tl, b2f, aoutf, tmp, nullptr, nullptr, M, 512, 2048);
    ln_kernel<0><<<M, 256, 0, stream>>>(tmp, ln2g, ln2b, outMain, nullptr, nullptr);

    (void)in_sizes; (void)n_in; (void)out_size; (void)ws_size;
}

// Round 5
// 613.953 us; speedup vs baseline: 1.2853x; 1.2853x over previous
//
#include <hip/hip_runtime.h>
#include <hip/hip_bf16.h>

typedef __bf16 bf16;
typedef __bf16 bf16x8 __attribute__((ext_vector_type(8)));
typedef __bf16 bf16x4 __attribute__((ext_vector_type(4)));
typedef float f32x4 __attribute__((ext_vector_type(4)));

#define S_LEN 2048
#define D_MOD 512
#define NHEAD 8
#define DHEAD 64
#define NBATCH 2

// async global->LDS, 16B per lane; LDS dest is wave-uniform base + lane*16
#define GLOAD_LDS(g, l) __builtin_amdgcn_global_load_lds( \
    (const __attribute__((address_space(1))) unsigned int*)(g), \
    (__attribute__((address_space(3))) unsigned int*)(l), 16, 0, 0)

// flags[1]: mask mode: 0 = 4-byte elems (int32/fp32), 1 = 1-byte, 2 = 2-byte (bf16)
__global__ void detect_kernel(const unsigned char* __restrict__ m, int* __restrict__ flags) {
    __shared__ int s4[4];
    int t = threadIdx.x;
    if (t < 4) s4[t] = 0;
    __syncthreads();
    int c3F = 0, c80p0 = 0, cnzo = 0;
    for (int i = t; i < 4096; i += 256) {
        unsigned b = m[i];
        c3F += (b == 0x3F);
        c80p0 += ((b == 0x80) && ((i & 3) == 0));
        cnzo += ((b != 0) && ((i & 3) != 0));
    }
    atomicAdd(&s4[1], c3F);
    atomicAdd(&s4[2], c80p0);
    atomicAdd(&s4[3], cnzo);
    __syncthreads();
    if (t == 0) {
        int mode;
        if (s4[1] > 0)      mode = (s4[2] > 0) ? 2 : 0;
        else if (s4[3] > 0) mode = 1;
        else                mode = 0;
        flags[1] = mode;
    }
}

__global__ void maskconv_kernel(const unsigned char* __restrict__ m,
                                const int* __restrict__ flags,
                                unsigned char* __restrict__ out) {
    long i = ((long)blockIdx.x * 256 + threadIdx.x) * 4;
    int mode = flags[1];
    uchar4 v;
    if (mode == 0) {
        const int* mi = (const int*)m;
        v.x = (unsigned char)(mi[i + 0] != 0);
        v.y = (unsigned char)(mi[i + 1] != 0);
        v.z = (unsigned char)(mi[i + 2] != 0);
        v.w = (unsigned char)(mi[i + 3] != 0);
    } else if (mode == 1) {
        uchar4 r = *(const uchar4*)(m + i);
        v.x = (r.x != 0); v.y = (r.y != 0); v.z = (r.z != 0); v.w = (r.w != 0);
    } else {
        const unsigned short* ms = (const unsigned short*)m;
        v.x = (unsigned char)(ms[i + 0] != 0);
        v.y = (unsigned char)(ms[i + 1] != 0);
        v.z = (unsigned char)(ms[i + 2] != 0);
        v.w = (unsigned char)(ms[i + 3] != 0);
    }
    *(uchar4*)(out + i) = v;
}

// ---------- fp32 -> (hi,lo) bf16 split, elementwise ----------
__global__ __launch_bounds__(256) void packA(const float* __restrict__ src,
                                             bf16* __restrict__ outh,
                                             bf16* __restrict__ outl) {
    long i = ((long)blockIdx.x * 256 + threadIdx.x) * 4;
    f32x4 v = *(const f32x4*)(src + i);
    bf16x4 h, l;
    #pragma unroll
    for (int j = 0; j < 4; ++j) {
        bf16 hh = (bf16)v[j];
        h[j] = hh;
        l[j] = (bf16)(v[j] - (float)hh);
    }
    *(bf16x4*)(outh + i) = h;
    *(bf16x4*)(outl + i) = l;
}

// ---------- ALL weight prep in one kernel: transpose+split 6 weights + bias concat ----
// blocks 0-63: Wq ; 64-127: Wk ; 128-191: Wv ; 192-255: Wo ; 256-511: W1 ; 512-767: W2 ;
// 768-773: bqkv concat.
__global__ __launch_bounds__(256) void packW_all(
    const float* __restrict__ Wq, const float* __restrict__ Wk,
    const float* __restrict__ Wv, const float* __restrict__ Wo,
    const float* __restrict__ W1, const float* __restrict__ W2,
    const float* __restrict__ bq, const float* __restrict__ bk,
    const float* __restrict__ bv,
    bf16* __restrict__ WqkvTh, bf16* __restrict__ WqkvTl,
    bf16* __restrict__ WoTh, bf16* __restrict__ WoTl,
    bf16* __restrict__ W1Th, bf16* __restrict__ W1Tl,
    bf16* __restrict__ W2Th, bf16* __restrict__ W2Tl,
    float* __restrict__ bqkv)
{
    __shared__ float tile[64][65];
    int blk = blockIdx.x, t = threadIdx.x;
    if (blk >= 768) {
        int i = (blk - 768) * 256 + t;
        bqkv[i] = (i < 512) ? bq[i] : (i < 1024 ? bk[i - 512] : bv[i - 1024]);
        return;
    }
    const float* W; bf16* oh; bf16* ol; int K, N, lb, sh; long dofs = 0;
    if (blk < 256) {
        lb = blk & 63; K = 512; N = 512; sh = 3;
        if (blk < 64)       { W = Wq; oh = WqkvTh; ol = WqkvTl; }
        else if (blk < 128) { W = Wk; oh = WqkvTh; ol = WqkvTl; dofs = 512 * 512; }
        else if (blk < 192) { W = Wv; oh = WqkvTh; ol = WqkvTl; dofs = (long)2 * 512 * 512; }
        else                { W = Wo; oh = WoTh;   ol = WoTl; }
    } else if (blk < 512) { lb = blk - 256; W = W1; oh = W1Th; ol = W1Tl; K = 512;  N = 2048; sh = 5; }
    else                  { lb = blk - 512; W = W2; oh = W2Th; ol = W2Tl; K = 2048; N = 512;  sh = 3; }
    int n0 = (lb & ((1 << sh) - 1)) * 64, k0 = (lb >> sh) * 64;
    int tx = t & 63, ty = t >> 6;
    #pragma unroll
    for (int r = ty; r < 64; r += 4)
        tile[r][tx] = W[(long)(k0 + r) * N + n0 + tx];
    __syncthreads();
    #pragma unroll
    for (int r = ty; r < 64; r += 4) {
        float v = tile[tx][r];            // = W[k0+tx][n0+r]
        bf16 h = (bf16)v;
        long idx = dofs + (long)(n0 + r) * K + k0 + tx;
        oh[idx] = h;
        ol[idx] = (bf16)(v - (float)h);
    }
}

// ---------- split-bf16 MFMA GEMM, shape-adaptive tile ----------
// C[M,N] = (Ahi+Alo)[M,K] @ (Bth+Btl)[N,K]^T ; 3-term: hi*hi + hi*lo + lo*hi.
// LDS is one flat chunk-ordered region: [Ahi BM | Alo BM | Bhi BN | Blo BN] rows x 32.
// EPI 1: +bias, relu -> (hi,lo) bf16 pair
// EPI 2: +bias +res  -> fp32
// EPI 3: fused QKV: n<512 -> outh bf16 ; n<1024 -> outl bf16 ; else outf fp32
template<int BM, int BN, int WR, int WC, int EPI>
__global__ __launch_bounds__(256) void mgemm(
    const bf16* __restrict__ Ahi, const bf16* __restrict__ Alo,
    const bf16* __restrict__ Bth, const bf16* __restrict__ Btl,
    const float* __restrict__ bias, const float* __restrict__ res,
    float* __restrict__ outf, bf16* __restrict__ outh, bf16* __restrict__ outl,
    int M, int N, int K)
{
    constexpr int WM = BM / WR, WN = BN / WC;
    constexpr int FI = WM / 16, FJ = WN / 16;
    constexpr int NCH = (2 * BM + 2 * BN) / 16;   // 16-row chunks
    constexpr int NPW = NCH / 4;                  // chunks per wave
    __shared__ bf16 lds[(2 * BM + 2 * BN) * 32];

    int t = threadIdx.x;
    int lane = t & 63, wave = t >> 6;
    int lm = lane & 15, quad = lane >> 4;
    int wr = wave / WC, wc = wave % WC;
    int m0 = blockIdx.y * BM, n0 = blockIdx.x * BN;

    // per-chunk global pointers (16 rows x 32 cols each; 4 lanes/row x 16B)
    const bf16* gp[NPW];
    #pragma unroll
    for (int ci = 0; ci < NPW; ++ci) {
        int c = wave * NPW + ci;
        const bf16* src; int row0;
        if (c < BM / 16)                  { src = Ahi; row0 = m0 + c * 16; }
        else if (c < 2 * BM / 16)         { src = Alo; row0 = m0 + (c - BM / 16) * 16; }
        else if (c < (2 * BM + BN) / 16)  { src = Bth; row0 = n0 + (c - 2 * BM / 16) * 16; }
        else                              { src = Btl; row0 = n0 + (c - (2 * BM + BN) / 16) * 16; }
        gp[ci] = src + (long)(row0 + (lane >> 2)) * K + (lane & 3) * 8;
    }
    bf16* ldsw = &lds[wave * NPW * 512];

    f32x4 acc[FI][FJ] = {};

    for (int k0 = 0; k0 < K; k0 += 32) {
        __syncthreads();                       // all waves done reading prev tile
        #pragma unroll
        for (int ci = 0; ci < NPW; ++ci)
            GLOAD_LDS(gp[ci] + k0, ldsw + ci * 512);
        __syncthreads();                       // drains vmcnt -> LDS valid

        bf16x8 ah[FI], al[FI];
        #pragma unroll
        for (int i = 0; i < FI; ++i) {
            int row = wr * WM + i * 16 + lm;
            ah[i] = *(const bf16x8*)&lds[row * 32 + quad * 8];
            al[i] = *(const bf16x8*)&lds[(BM + row) * 32 + quad * 8];
        }
        #pragma unroll
        for (int j = 0; j < FJ; ++j) {
            int row = wc * WN + j * 16 + lm;
            bf16x8 bh = *(const bf16x8*)&lds[(2 * BM + row) * 32 + quad * 8];
            bf16x8 bl = *(const bf16x8*)&lds[(2 * BM + BN + row) * 32 + quad * 8];
            #pragma unroll
            for (int i = 0; i < FI; ++i) {
                acc[i][j] = __builtin_amdgcn_mfma_f32_16x16x32_bf16(ah[i], bh, acc[i][j], 0, 0, 0);
                acc[i][j] = __builtin_amdgcn_mfma_f32_16x16x32_bf16(ah[i], bl, acc[i][j], 0, 0, 0);
                acc[i][j] = __builtin_amdgcn_mfma_f32_16x16x32_bf16(al[i], bh, acc[i][j], 0, 0, 0);
            }
        }
    }

    #pragma unroll
    for (int j = 0; j < FJ; ++j) {
        int gn = n0 + wc * WN + j * 16 + lm;
        float bv = bias[gn];
        #pragma unroll
        for (int i = 0; i < FI; ++i) {
            #pragma unroll
            for (int r = 0; r < 4; ++r) {
                int gm = m0 + wr * WM + i * 16 + quad * 4 + r;
                float v = acc[i][j][r] + bv;
                if (EPI == 3) {
                    if (gn < 512)       outh[(long)gm * 512 + gn] = (bf16)v;
                    else if (gn < 1024) outl[(long)gm * 512 + gn - 512] = (bf16)v;
                    else                outf[(long)gm * 512 + gn - 1024] = v;
                } else {
                    long idx = (long)gm * N + gn;
                    if (EPI == 1) {
                        v = fmaxf(v, 0.f);
                        bf16 h = (bf16)v;
                        outh[idx] = h;
                        outl[idx] = (bf16)(v - (float)h);
                    } else {
                        if (EPI == 2) v += res[idx];
                        outf[idx] = v;
                    }
                }
            }
        }
    }
}

// ---------- V fp32 [B*S, H*64] -> bf16 V^T [B,H,64,S], LDS-tiled (coalesced) ----------
__global__ __launch_bounds__(256) void pack_vT(const float* __restrict__ src,
                                               bf16* __restrict__ dst) {
    __shared__ float tile[64][65];
    int s0 = blockIdx.x * 64;
    int bh = blockIdx.y;             // b*8+h
    int b = bh >> 3, h = bh & 7;
    int t = threadIdx.x, tx = t & 63, ty = t >> 6;
    #pragma unroll
    for (int r = ty; r < 64; r += 4)
        tile[r][tx] = src[(long)(b * S_LEN + s0 + r) * 512 + h * 64 + tx];
    __syncthreads();
    #pragma unroll
    for (int d = ty; d < 64; d += 4)
        dst[((long)bh * 64 + d) * S_LEN + s0 + tx] = (bf16)tile[tx][d];
}

// ---------- MFMA attention: two-pass softmax, async double-buffered K/V staging ----------
// K/V tiles staged via global_load_lds into linear LDS with XOR slot swizzle:
// LDS[row][s] holds global[row][s ^ (row&7)] (16B slots); reads XOR back -> 2-way banks.
// One barrier per k-tile: issue next tile's loads, compute current, __syncthreads (drains vmcnt).
// Q,K layout: bf16 [B*S, 512] (head h at col h*64). V^T layout: bf16 [B,H,64,S].
__global__ __launch_bounds__(256) void attn_kernel(
    const bf16* __restrict__ Q, const bf16* __restrict__ Kg,
    const bf16* __restrict__ Vt, const unsigned char* __restrict__ mask8,
    float* __restrict__ attnO, bf16* __restrict__ ctxh, bf16* __restrict__ ctxl)
{
    __shared__ bf16 Qs[64][72];
    __shared__ bf16 Ks[2][64 * 64];
    __shared__ bf16 Vs[2][64 * 64];
    __shared__ bf16 Ps[64][72];

    int t = threadIdx.x;
    int qt = blockIdx.x & 31, bh = blockIdx.x >> 5;
    int b_ = bh >> 3, h_ = bh & 7;
    int q0 = qt * 64;
    int lane = t & 63, wave = t >> 6;
    int lm = lane & 15, quad = lane >> 4, q8 = quad * 8;
    int sr = t >> 2, sc = (t & 3) * 16;

    // staging lane geometry: one GLOAD covers 8 rows x 64 cols (64 lanes x 16B)
    int srow8 = lane >> 3;                 // row within 8-row group == row&7
    int sslot = (lane & 7) ^ srow8;        // swizzled 16B slot to FETCH from global

    const bf16* Qp = Q + (((long)(b_ * S_LEN + q0 + sr)) << 9) + (h_ << 6) + sc;
    *(bf16x8*)&Qs[sr][sc]     = *(const bf16x8*)(Qp);
    *(bf16x8*)&Qs[sr][sc + 8] = *(const bf16x8*)(Qp + 8);
    __syncthreads();
    // Q fragments are loop-invariant: hoist
    bf16x8 a0 = *(const bf16x8*)&Qs[wave * 16 + lm][q8];
    bf16x8 a1 = *(const bf16x8*)&Qs[wave * 16 + lm][32 + q8];

    float mrow[4], lrow[4];
    #pragma unroll
    for (int r = 0; r < 4; ++r) { mrow[r] = -1e30f; lrow[r] = 0.f; }

    const unsigned char* Mbase = mask8 + (long)b_ * S_LEN * S_LEN;
    const bf16* Kbase = Kg + (((long)(b_ * S_LEN)) << 9) + (h_ << 6);
    const bf16* Vbase = Vt + (long)bh * (DHEAD * S_LEN);

    // ---------------- pass 1: row max + sum(exp) ----------------
    {
        #pragma unroll
        for (int c = 0; c < 2; ++c) {
            int rl = wave * 16 + c * 8;
            GLOAD_LDS(Kbase + (long)(rl + srow8) * 512 + sslot * 8, &Ks[0][rl * 64]);
        }
        __syncthreads();
        int cur = 0;
        for (int kt = 0; kt < 32; ++kt) {
            int k0 = kt * 64;
            if (kt < 31) {
                #pragma unroll
                for (int c = 0; c < 2; ++c) {
                    int rl = wave * 16 + c * 8;
                    GLOAD_LDS(Kbase + (long)(k0 + 64 + rl + srow8) * 512 + sslot * 8,
                              &Ks[cur ^ 1][rl * 64]);
                }
            }
            const bf16* kc = Ks[cur];
            f32x4 sacc[4] = {};
            #pragma unroll
            for (int tn = 0; tn < 4; ++tn) {
                int row = tn * 16 + lm, sw = row & 7;
                bf16x8 b0 = *(const bf16x8*)&kc[row * 64 + ((quad ^ sw) << 3)];
                bf16x8 b1 = *(const bf16x8*)&kc[row * 64 + (((4 | quad) ^ sw) << 3)];
                sacc[tn] = __builtin_amdgcn_mfma_f32_16x16x32_bf16(a0, b0, sacc[tn], 0, 0, 0);
                sacc[tn] = __builtin_amdgcn_mfma_f32_16x16x32_bf16(a1, b1, sacc[tn], 0, 0, 0);
            }
            #pragma unroll
            for (int r = 0; r < 4; ++r) {
                int grow = q0 + wave * 16 + quad * 4 + r;
                const unsigned char* Mr = Mbase + (long)grow * S_LEN + k0 + lm;
                float sv[4];
                float tmax = -1e30f;
                #pragma unroll
                for (int tn = 0; tn < 4; ++tn) {
                    float s = sacc[tn][r] * 0.125f;
                    if (Mr[tn * 16]) s = -1e9f;
                    sv[tn] = s;
                    tmax = fmaxf(tmax, s);
                }
                #pragma unroll
                for (int off = 8; off; off >>= 1) tmax = fmaxf(tmax, __shfl_xor(tmax, off));
                float mnew = fmaxf(mrow[r], tmax);
                float es = 0.f;
                #pragma unroll
                for (int tn = 0; tn < 4; ++tn) es += __expf(sv[tn] - mnew);
                #pragma unroll
                for (int off = 8; off; off >>= 1) es += __shfl_xor(es, off);
                lrow[r] = lrow[r] * __expf(mrow[r] - mnew) + es;
                mrow[r] = mnew;
            }
            __syncthreads();        // drains vmcnt -> next buffer ready; all waves done reading cur
            cur ^= 1;
        }
    }
    float rl4[4];
    #pragma unroll
    for (int r = 0; r < 4; ++r) rl4[r] = 1.f / lrow[r];

    float* attnBase = attnO + (long)bh * S_LEN * S_LEN;
    f32x4 oacc[4] = {};

    // ---------------- pass 2: recompute scores, write fp32 probs, accumulate PV ----------------
    {
        #pragma unroll
        for (int c = 0; c < 2; ++c) {
            int rl = wave * 16 + c * 8;
            GLOAD_LDS(Kbase + (long)(rl + srow8) * 512 + sslot * 8, &Ks[0][rl * 64]);
            GLOAD_LDS(Vbase + (long)(rl + srow8) * S_LEN + sslot * 8, &Vs[0][rl * 64]);
        }
        __syncthreads();
        int cur = 0;
        for (int kt = 0; kt < 32; ++kt) {
            int k0 = kt * 64;
            if (kt < 31) {
                #pragma unroll
                for (int c = 0; c < 2; ++c) {
                    int rl = wave * 16 + c * 8;
                    GLOAD_LDS(Kbase + (long)(k0 + 64 + rl + srow8) * 512 + sslot * 8,
                              &Ks[cur ^ 1][rl * 64]);
                    GLOAD_LDS(Vbase + (long)(rl + srow8) * S_LEN + k0 + 64 + sslot * 8,
                              &Vs[cur ^ 1][rl * 64]);
                }
            }
            const bf16* kc = Ks[cur];
            const bf16* vc = Vs[cur];
            f32x4 sacc[4] = {};
            #pragma unroll
            for (int tn = 0; tn < 4; ++tn) {
                int row = tn * 16 + lm, sw = row & 7;
                bf16x8 b0 = *(const bf16x8*)&kc[row * 64 + ((quad ^ sw) << 3)];
                bf16x8 b1 = *(const bf16x8*)&kc[row * 64 + (((4 | quad) ^ sw) << 3)];
                sacc[tn] = __builtin_amdgcn_mfma_f32_16x16x32_bf16(a0, b0, sacc[tn], 0, 0, 0);
                sacc[tn] = __builtin_amdgcn_mfma_f32_16x16x32_bf16(a1, b1, sacc[tn], 0, 0, 0);
            }
            #pragma unroll
            for (int r = 0; r < 4; ++r) {
                int grow = q0 + wave * 16 + quad * 4 + r;
                const unsigned char* Mr = Mbase + (long)grow * S_LEN + k0 + lm;
                #pragma unroll
                for (int tn = 0; tn < 4; ++tn) {
                    float s = sacc[tn][r] * 0.125f;
                    if (Mr[tn * 16]) s = -1e9f;
                    float p = __expf(s - mrow[r]) * rl4[r];
                    attnBase[(long)grow * S_LEN + k0 + tn * 16 + lm] = p;
                    Ps[wave * 16 + quad * 4 + r][tn * 16 + lm] = (bf16)p;
                }
            }
            // PV: Ps rows are within-wave (written+read by same wave); Vs[cur] ready since prev barrier
            bf16x8 pa0 = *(const bf16x8*)&Ps[wave * 16 + lm][q8];
            bf16x8 pa1 = *(const bf16x8*)&Ps[wave * 16 + lm][32 + q8];
            #pragma unroll
            for (int td = 0; td < 4; ++td) {
                int row = td * 16 + lm, sw = row & 7;
                bf16x8 v0 = *(const bf16x8*)&vc[row * 64 + ((quad ^ sw) << 3)];
                bf16x8 v1 = *(const bf16x8*)&vc[row * 64 + (((4 | quad) ^ sw) << 3)];
                oacc[td] = __builtin_amdgcn_mfma_f32_16x16x32_bf16(pa0, v0, oacc[td], 0, 0, 0);
                oacc[td] = __builtin_amdgcn_mfma_f32_16x16x32_bf16(pa1, v1, oacc[td], 0, 0, 0);
            }
            __syncthreads();
            cur ^= 1;
        }
    }

    // ctx bf16 hi/lo [B*S, H*64]
    #pragma unroll
    for (int td = 0; td < 4; ++td)
    #pragma unroll
    for (int r = 0; r < 4; ++r) {
        int grow = q0 + wave * 16 + quad * 4 + r;
        long cidx = (((long)(b_ * S_LEN + grow)) << 9) + (h_ << 6) + td * 16 + lm;
        float v = oacc[td][r];
        bf16 h = (bf16)v;
        ctxh[cidx] = h;
        ctxl[cidx] = (bf16)(v - (float)h);
    }
}

// ---------- layernorm over D=512; optional hi/lo bf16 split outputs ----------
template<int SPLIT>
__global__ __launch_bounds__(256) void ln_kernel(
    const float* __restrict__ X, const float* __restrict__ g,
    const float* __restrict__ bb, float* __restrict__ out,
    bf16* __restrict__ oh, bf16* __restrict__ ol)
{
    __shared__ float red[8];
    int row = blockIdx.x, t = threadIdx.x;
    float x0 = X[(long)row * 512 + t];
    float x1 = X[(long)row * 512 + 256 + t];
    float s = x0 + x1, ss = x0 * x0 + x1 * x1;
    #pragma unroll
    for (int off = 32; off; off >>= 1) { s += __shfl_xor(s, off); ss += __shfl_xor(ss, off); }
    if ((t & 63) == 0) { red[t >> 6] = s; red[4 + (t >> 6)] = ss; }
    __syncthreads();
    float S_ = red[0] + red[1] + red[2] + red[3];
    float SS = red[4] + red[5] + red[6] + red[7];
    float mu = S_ * (1.f / 512.f);
    float var = SS * (1.f / 512.f) - mu * mu;
    float is = rsqrtf(var + 1e-5f);
    float o0 = (x0 - mu) * is * g[t]       + bb[t];
    float o1 = (x1 - mu) * is * g[t + 256] + bb[t + 256];
    out[(long)row * 512 + t]       = o0;
    out[(long)row * 512 + 256 + t] = o1;
    if (SPLIT) {
        bf16 h0 = (bf16)o0, h1 = (bf16)o1;
        oh[(long)row * 512 + t]       = h0;
        oh[(long)row * 512 + 256 + t] = h1;
        ol[(long)row * 512 + t]       = (bf16)(o0 - (float)h0);
        ol[(long)row * 512 + 256 + t] = (bf16)(o1 - (float)h1);
    }
}

// ---------------- host launch ----------------
extern "C" void kernel_launch(void* const* d_in, const int* in_sizes, int n_in,
                              void* d_out, int out_size, void* d_ws, size_t ws_size,
                              hipStream_t stream)
{
    const float* x = (const float*)d_in[0];
    const unsigned char* maskraw = (const unsigned char*)d_in[1];
    const float* Wq = (const float*)d_in[2];  const float* bq = (const float*)d_in[3];
    const float* Wk = (const float*)d_in[4];  const float* bk = (const float*)d_in[5];
    const float* Wv = (const float*)d_in[6];  const float* bv = (const float*)d_in[7];
    const float* Wo = (const float*)d_in[8];  const float* bo = (const float*)d_in[9];
    const float* ln1g = (const float*)d_in[10]; const float* ln1b = (const float*)d_in[11];
    const float* W1 = (const float*)d_in[12]; const float* b1f = (const float*)d_in[13];
    const float* W2 = (const float*)d_in[14]; const float* b2f = (const float*)d_in[15];
    const float* ln2g = (const float*)d_in[16]; const float* ln2b = (const float*)d_in[17];

    // OUTPUTS ARE FP32: out [B*S*D] then attn [B*H*S*S], concatenated flat.
    float* outMain = (float*)d_out;
    float* outAttn = outMain + (size_t)NBATCH * S_LEN * D_MOD;

    char* w = (char*)d_ws;
    size_t off = 0;
    auto alloc = [&](size_t bytes) -> char* {
        char* p = w + off;
        off += (bytes + 255) & ~(size_t)255;
        return p;
    };
    const size_t MB = 1024 * 1024;
    int* flags = (int*)alloc(256);
    unsigned char* mask8 = (unsigned char*)alloc(8 * MB);

    // ---- 36MB contiguous span (later aliased by hh/hl for FFN hidden) ----
    bf16* xh   = (bf16*)alloc(4 * MB);   // input x hi  [4096,512]
    bf16* xl   = (bf16*)alloc(4 * MB);   // input x lo
    bf16* Qb   = (bf16*)alloc(4 * MB);   // Q bf16 [4096,512]
    bf16* Kb   = (bf16*)alloc(4 * MB);   // K bf16 [4096,512]
    float* vf  = (float*)alloc(8 * MB);  // V fp32 [4096,512]
    bf16* Vtb  = (bf16*)alloc(4 * MB);   // V^T bf16 [B,H,64,S]
    bf16* ctxh = (bf16*)alloc(4 * MB);   // ctx hi
    bf16* ctxl = (bf16*)alloc(4 * MB);   // ctx lo
    // aliases: FFN hidden [4096,2048] bf16 hi/lo, 16MB each
    bf16* hh = xh;            // covers xh,xl,Qb,Kb   (all dead before FFN1)
    bf16* hl = (bf16*)vf;     // covers vf,Vtb,ctxh   (all dead before FFN1)

    float* tmp   = (float*)alloc(8 * MB);
    float* aoutf = (float*)alloc(8 * MB);
    bf16* aouth  = (bf16*)alloc(4 * MB);
    bf16* aoutl  = (bf16*)alloc(4 * MB);

    // weights: transposed+split
    bf16* WqkvTh = (bf16*)alloc((size_t)1536 * 512 * 2);
    bf16* WqkvTl = (bf16*)alloc((size_t)1536 * 512 * 2);
    bf16* WoTh = (bf16*)alloc(512 * 1024); bf16* WoTl = (bf16*)alloc(512 * 1024);
    bf16* W1Th = (bf16*)alloc(2 * MB);     bf16* W1Tl = (bf16*)alloc(2 * MB);
    bf16* W2Th = (bf16*)alloc(2 * MB);     bf16* W2Tl = (bf16*)alloc(2 * MB);
    float* bqkv = (float*)alloc(1536 * 4);

    const int M = NBATCH * S_LEN;  // 4096

    detect_kernel<<<1, 256, 0, stream>>>(maskraw, flags);
    maskconv_kernel<<<(NBATCH * S_LEN * S_LEN) / 1024, 256, 0, stream>>>(maskraw, flags, mask8);

    // all weight prep in one launch
    packW_all<<<774, 256, 0, stream>>>(Wq, Wk, Wv, Wo, W1, W2, bq, bk, bv,
                                       WqkvTh, WqkvTl, WoTh, WoTl,
                                       W1Th, W1Tl, W2Th, W2Tl, bqkv);

    // fused QKV projection -> Qb/Kb bf16 (attn layout) + vf fp32
    packA<<<(M * 512) / 1024, 256, 0, stream>>>(x, xh, xl);
    mgemm<64, 128, 1, 4, 3><<<dim3(12, 64), 256, 0, stream>>>(
        xh, xl, WqkvTh, WqkvTl, bqkv, nullptr, vf, Qb, Kb, M, 1536, 512);
    pack_vT<<<dim3(32, 16), 256, 0, stream>>>(vf, Vtb);

    // fused two-pass MFMA attention: fp32 probs (Output 1) + bf16 hi/lo context
    attn_kernel<<<512, 256, 0, stream>>>(Qb, Kb, Vtb, mask8, outAttn, ctxh, ctxl);

    // out-proj + residual, then LN1 (emits hi/lo for FFN1)
    mgemm<64, 64, 2, 2, 2><<<dim3(8, 64), 256, 0, stream>>>(
        ctxh, ctxl, WoTh, WoTl, bo, x, tmp, nullptr, nullptr, M, 512, 512);
    ln_kernel<1><<<M, 256, 0, stream>>>(tmp, ln1g, ln1b, aoutf, aouth, aoutl);

    // FFN: W1 emits relu'd (hi,lo) bf16 directly
    mgemm<128, 128, 2, 2, 1><<<dim3(16, 32), 256, 0, stream>>>(
        aouth, aoutl, W1Th, W1Tl, b1f, nullptr, nullptr, hh, hl, M, 2048, 512);
    mgemm<64, 64, 2, 2, 2><<<dim3(8, 64), 256, 0, stream>>>(
        hh, hl, W2Th, W2Tl, b2f, aoutf, tmp, nullptr, nullptr, M, 512, 2048);
    ln_kernel<0><<<M, 256, 0, stream>>>(tmp, ln2g, ln2b, outMain, nullptr, nullptr);

    (void)in_sizes; (void)n_in; (void)out_size; (void)ws_size;
}